// Round 1
// baseline (113.503 us; speedup 1.0000x reference)
//
#include <hip/hip_runtime.h>

// Sheaf Dirichlet energy (normalize=False):
//   loss = sum_e || maps[rev[e]] @ x[tgt[e]] - maps[e] @ x[src[e]] ||_F^2
// Edge set is symmetric: edge e (< E/2) and its reverse e+E/2 contribute
// identical squared norms (diff is exactly negated), so we compute the first
// half and double — each restriction map is then read exactly once from HBM.

#define DD 4
#define FF 16

__device__ __forceinline__ float getc(const float4& v, int j) {
    switch (j) { case 0: return v.x; case 1: return v.y; case 2: return v.z; default: return v.w; }
}

__device__ __forceinline__ void fma4(float4& d, float m, const float4& v) {
    d.x = fmaf(m, v.x, d.x);
    d.y = fmaf(m, v.y, d.y);
    d.z = fmaf(m, v.z, d.z);
    d.w = fmaf(m, v.w, d.w);
}

__global__ void zero_out_kernel(float* out) {
    if (threadIdx.x == 0 && blockIdx.x == 0) out[0] = 0.0f;
}

__global__ __launch_bounds__(256) void sheaf_energy_kernel(
    const float* __restrict__ x,          // [N, 4, 16]
    const float* __restrict__ maps,       // [E, 4, 4]
    const int*   __restrict__ edge_index, // [2, E] flat
    const int*   __restrict__ rev_idx,    // [E]
    float* __restrict__ out,
    int eHalf, int E)
{
    const int e = blockIdx.x * blockDim.x + threadIdx.x;
    float ssum = 0.0f;

    if (e < eHalf) {
        const int s = edge_index[e];         // src
        const int t = edge_index[E + e];     // tgt
        const int r = rev_idx[e];            // reverse edge id (= e + eHalf structurally)

        const float4* __restrict__ M1p = reinterpret_cast<const float4*>(maps + (size_t)r * 16); // Fvu
        const float4* __restrict__ M2p = reinterpret_cast<const float4*>(maps + (size_t)e * 16); // Fuv
        float4 M1[4], M2[4];
        #pragma unroll
        for (int i = 0; i < 4; ++i) M1[i] = M1p[i];
        #pragma unroll
        for (int i = 0; i < 4; ++i) M2[i] = M2p[i];

        const float4* __restrict__ xt = reinterpret_cast<const float4*>(x + (size_t)t * (DD * FF));
        const float4* __restrict__ xs = reinterpret_cast<const float4*>(x + (size_t)s * (DD * FF));

        // diff[i][q] is the q-th float4 chunk (features 4q..4q+3) of output row i
        float4 diff[4][4];
        #pragma unroll
        for (int i = 0; i < 4; ++i)
            #pragma unroll
            for (int q = 0; q < 4; ++q)
                diff[i][q] = make_float4(0.f, 0.f, 0.f, 0.f);

        // += M1 @ x[t]
        #pragma unroll
        for (int j = 0; j < 4; ++j) {
            const float4 c0 = xt[4*j+0], c1 = xt[4*j+1], c2 = xt[4*j+2], c3 = xt[4*j+3];
            #pragma unroll
            for (int i = 0; i < 4; ++i) {
                const float m = getc(M1[i], j);
                fma4(diff[i][0], m, c0);
                fma4(diff[i][1], m, c1);
                fma4(diff[i][2], m, c2);
                fma4(diff[i][3], m, c3);
            }
        }
        // -= M2 @ x[s]
        #pragma unroll
        for (int j = 0; j < 4; ++j) {
            const float4 c0 = xs[4*j+0], c1 = xs[4*j+1], c2 = xs[4*j+2], c3 = xs[4*j+3];
            #pragma unroll
            for (int i = 0; i < 4; ++i) {
                const float m = -getc(M2[i], j);
                fma4(diff[i][0], m, c0);
                fma4(diff[i][1], m, c1);
                fma4(diff[i][2], m, c2);
                fma4(diff[i][3], m, c3);
            }
        }

        float ss = 0.0f;
        #pragma unroll
        for (int i = 0; i < 4; ++i) {
            #pragma unroll
            for (int q = 0; q < 4; ++q) {
                ss = fmaf(diff[i][q].x, diff[i][q].x, ss);
                ss = fmaf(diff[i][q].y, diff[i][q].y, ss);
                ss = fmaf(diff[i][q].z, diff[i][q].z, ss);
                ss = fmaf(diff[i][q].w, diff[i][q].w, ss);
            }
        }
        ssum = ss;
    }

    // wave64 reduction
    #pragma unroll
    for (int off = 32; off > 0; off >>= 1)
        ssum += __shfl_down(ssum, off, 64);

    __shared__ float wave_sums[4];
    const int lane = threadIdx.x & 63;
    const int wid  = threadIdx.x >> 6;
    if (lane == 0) wave_sums[wid] = ssum;
    __syncthreads();
    if (threadIdx.x == 0) {
        const float bs = wave_sums[0] + wave_sums[1] + wave_sums[2] + wave_sums[3];
        atomicAdd(out, 2.0f * bs);  // ×2: reverse-edge contributions are identical
    }
}

extern "C" void kernel_launch(void* const* d_in, const int* in_sizes, int n_in,
                              void* d_out, int out_size, void* d_ws, size_t ws_size,
                              hipStream_t stream) {
    const float* x          = (const float*)d_in[0];
    const float* maps       = (const float*)d_in[1];
    const int*   edge_index = (const int*)d_in[2];
    const int*   rev_idx    = (const int*)d_in[3];
    float* out = (float*)d_out;

    const int E     = in_sizes[3];   // rev_idx has one entry per directed edge
    const int eHalf = E / 2;

    zero_out_kernel<<<1, 64, 0, stream>>>(out);

    const int block = 256;
    const int grid  = (eHalf + block - 1) / block;
    sheaf_energy_kernel<<<grid, block, 0, stream>>>(x, maps, edge_index, rev_idx, out, eHalf, E);
}

// Round 2
// 108.670 us; speedup vs baseline: 1.0445x; 1.0445x over previous
//
#include <hip/hip_runtime.h>

// Sheaf Dirichlet energy (normalize=False):
//   loss = sum_e || maps[rev[e]] @ x[tgt[e]] - maps[e] @ x[src[e]] ||_F^2
// Symmetry: edge e (< E/2) and its reverse e+E/2 contribute identical squared
// norms, so compute the first half and double -> each map read exactly once.
//
// Work mapping (R2): 16 lanes per edge. Lane l owns output element
// (i = l>>2, q = l&3) of the 4x16 diff tile and loads only the four float4
// x-chunks x[row][j][4q..4q+3] (j=0..3) it needs. Lanes sharing q across i
// broadcast the same address; across q and edges, addresses are contiguous.
// This keeps every cache line fully used and cuts L1 line transactions ~4x
// vs the thread-per-edge private gather (which was TA-bound: VALU 9%, HBM 22%).

#define DD 4
#define FF 16
#define NE 8   // edges per 16-lane group (strided)

__device__ __forceinline__ void fma4(float4& d, float m, const float4& v) {
    d.x = fmaf(m, v.x, d.x);
    d.y = fmaf(m, v.y, d.y);
    d.z = fmaf(m, v.z, d.z);
    d.w = fmaf(m, v.w, d.w);
}

__global__ void zero_out_kernel(float* out) {
    if (threadIdx.x == 0 && blockIdx.x == 0) out[0] = 0.0f;
}

__global__ __launch_bounds__(256) void sheaf_energy_kernel(
    const float* __restrict__ x,          // [N, 4, 16]
    const float* __restrict__ maps,       // [E, 4, 4]
    const int*   __restrict__ edge_index, // [2, E] flat
    const int*   __restrict__ rev_idx,    // [E]
    float* __restrict__ out,
    int eHalf, int E, int nGroups)
{
    const int tid = blockIdx.x * blockDim.x + threadIdx.x;
    const int gid = tid >> 4;            // global 16-lane group id
    const int l   = threadIdx.x & 15;    // lane within group
    const int i   = l >> 2;              // output stalk row 0..3
    const int q   = l & 3;               // feature quarter 0..3

    float ssum = 0.0f;

    #pragma unroll 2
    for (int k = 0; k < NE; ++k) {
        const int e = gid + k * nGroups;
        if (e >= eHalf) break;

        const int s = edge_index[e];         // src
        const int t = edge_index[E + e];     // tgt
        const int r = rev_idx[e];            // reverse edge id

        // map rows: maps[r][i][:] and maps[e][i][:]  (16B each, 4-way lane broadcast)
        const float4 m1 = *reinterpret_cast<const float4*>(maps + (size_t)r * 16 + i * 4);
        const float4 m2 = *reinterpret_cast<const float4*>(maps + (size_t)e * 16 + i * 4);

        // x chunks this lane needs: x[row][j][4q..4q+3], j = 0..3
        const float* xtp = x + (size_t)t * (DD * FF) + q * 4;
        const float* xsp = x + (size_t)s * (DD * FF) + q * 4;
        const float4 xt0 = *reinterpret_cast<const float4*>(xtp);
        const float4 xt1 = *reinterpret_cast<const float4*>(xtp + 16);
        const float4 xt2 = *reinterpret_cast<const float4*>(xtp + 32);
        const float4 xt3 = *reinterpret_cast<const float4*>(xtp + 48);
        const float4 xs0 = *reinterpret_cast<const float4*>(xsp);
        const float4 xs1 = *reinterpret_cast<const float4*>(xsp + 16);
        const float4 xs2 = *reinterpret_cast<const float4*>(xsp + 32);
        const float4 xs3 = *reinterpret_cast<const float4*>(xsp + 48);

        float4 d = make_float4(0.f, 0.f, 0.f, 0.f);
        fma4(d,  m1.x, xt0);
        fma4(d,  m1.y, xt1);
        fma4(d,  m1.z, xt2);
        fma4(d,  m1.w, xt3);
        fma4(d, -m2.x, xs0);
        fma4(d, -m2.y, xs1);
        fma4(d, -m2.z, xs2);
        fma4(d, -m2.w, xs3);

        ssum = fmaf(d.x, d.x, ssum);
        ssum = fmaf(d.y, d.y, ssum);
        ssum = fmaf(d.z, d.z, ssum);
        ssum = fmaf(d.w, d.w, ssum);
    }

    // wave64 reduction
    #pragma unroll
    for (int off = 32; off > 0; off >>= 1)
        ssum += __shfl_down(ssum, off, 64);

    __shared__ float wave_sums[4];
    const int lane = threadIdx.x & 63;
    const int wid  = threadIdx.x >> 6;
    if (lane == 0) wave_sums[wid] = ssum;
    __syncthreads();
    if (threadIdx.x == 0) {
        const float bs = wave_sums[0] + wave_sums[1] + wave_sums[2] + wave_sums[3];
        atomicAdd(out, 2.0f * bs);  // x2: reverse-edge contributions identical
    }
}

extern "C" void kernel_launch(void* const* d_in, const int* in_sizes, int n_in,
                              void* d_out, int out_size, void* d_ws, size_t ws_size,
                              hipStream_t stream) {
    const float* x          = (const float*)d_in[0];
    const float* maps       = (const float*)d_in[1];
    const int*   edge_index = (const int*)d_in[2];
    const int*   rev_idx    = (const int*)d_in[3];
    float* out = (float*)d_out;

    const int E     = in_sizes[3];   // rev_idx: one entry per directed edge
    const int eHalf = E / 2;

    zero_out_kernel<<<1, 64, 0, stream>>>(out);

    const int block = 256;
    const int groupsPerBlock = block / 16;                         // 16
    const int grid = (eHalf + groupsPerBlock * NE - 1) / (groupsPerBlock * NE); // 6250
    const int nGroups = grid * groupsPerBlock;

    sheaf_energy_kernel<<<grid, block, 0, stream>>>(x, maps, edge_index, rev_idx,
                                                    out, eHalf, E, nGroups);
}